// Round 8
// baseline (67.452 us; speedup 1.0000x reference)
//
#include <hip/hip_runtime.h>
#include <hip/hip_bf16.h>

// GAT on MI355X. N=4096, DIN=512, H=128, K=4 heads, DOUT=16, p(adj)=0.01.
// D1 k_fused1: gemm1 (MFMA) || adj->bitmask (streaming).
// D2 k_attn1:  decode -> 1-pass logits (reg) -> pair-LDS -> 16B-gather -> ELU -> proj.
// D3 k_attn2:  fused decode+logits -> pair-LDS -> attn + log_softmax.

typedef __attribute__((ext_vector_type(4))) float floatx4;
typedef __attribute__((ext_vector_type(8))) short short8;
typedef __attribute__((ext_vector_type(4))) unsigned short ushortx4;
typedef __attribute__((ext_vector_type(4))) unsigned int uintx4;
typedef unsigned short u16b;

#define GN 4096
#define LDP 40   // LDS row stride in shorts (80B)

__device__ __forceinline__ u16b f2bf(float f) {
  union { float f; unsigned int i; } v; v.f = f;
  unsigned int r = v.i + 0x7FFF + ((v.i >> 16) & 1);   // RTN-even
  return (u16b)(r >> 16);
}
__device__ __forceinline__ float bflo(unsigned u) {
  union { unsigned i; float f; } v; v.i = u << 16; return v.f;
}
__device__ __forceinline__ float bfhi(unsigned u) {
  union { unsigned i; float f; } v; v.i = u & 0xffff0000u; return v.f;
}

// ---- D1: gemm1 (blocks 0..255) || bitmask build (blocks 256..2303). (unchanged)
__global__ __launch_bounds__(512) void k_fused1(const float* __restrict__ adj,
    const float* __restrict__ X, const float* __restrict__ W1,
    const float* __restrict__ as1, const float* __restrict__ ad1,
    u16b* __restrict__ mask, u16b* __restrict__ Wh1bf,
    float* __restrict__ src1t, float* __restrict__ dst1t) {
  int b = blockIdx.x, t = threadIdx.x;
  int lane = t & 63, w = t >> 6;
  if (b >= 256) {
    int n = (b - 256) * 2 + (t >> 8);
    int cg = t & 255;
    const float* ap = adj + (size_t)n * 4096 + cg * 16;
    floatx4 v0 = *(const floatx4*)(ap);
    floatx4 v1 = *(const floatx4*)(ap + 4);
    floatx4 v2 = *(const floatx4*)(ap + 8);
    floatx4 v3 = *(const floatx4*)(ap + 12);
    unsigned bits = 0;
#pragma unroll
    for (int i = 0; i < 4; ++i) {
      bits |= (unsigned)(v0[i] != 0.f) << i;
      bits |= (unsigned)(v1[i] != 0.f) << (4 + i);
      bits |= (unsigned)(v2[i] != 0.f) << (8 + i);
      bits |= (unsigned)(v3[i] != 0.f) << (12 + i);
    }
    if ((n >> 4) == cg) bits |= 1u << (n & 15);
    mask[(size_t)n * 256 + cg] = (u16b)bits;
  } else {
    __shared__ u16b Ab[64 * LDP];
    __shared__ u16b Bb[128 * LDP];
    __shared__ float sps[4][64], sds[4][64];
    int p = ((b >> 5) << 3) | (b & 7);
    int hd = (b >> 3) & 3;
    int rb = p * 64;
    const float* Wk = W1 + (size_t)hd * 65536;
    int wr = w >> 2, wc = w & 3, lh = lane >> 4, lm = lane & 15;
    int ar = t >> 2, aq = t & 3;
    int u = t - 256, kk0 = (u & 7) * 4, c0 = (u >> 3) * 4;
    floatx4 pa0, pa1, pb0, pb1, pb2, pb3;
    if (t < 256) {
      const float* ap = X + (size_t)(rb + ar) * 512 + aq * 8;
      pa0 = *(const floatx4*)(ap);
      pa1 = *(const floatx4*)(ap + 4);
    } else {
      const float* bp = Wk + (size_t)kk0 * 128 + c0;
      pb0 = *(const floatx4*)(bp);
      pb1 = *(const floatx4*)(bp + 128);
      pb2 = *(const floatx4*)(bp + 256);
      pb3 = *(const floatx4*)(bp + 384);
    }
    floatx4 acc[2][2] = {};
    for (int kk = 0; kk < 512; kk += 32) {
      if (t < 256) {
        short8 a;
        a[0] = (short)f2bf(pa0[0]); a[1] = (short)f2bf(pa0[1]);
        a[2] = (short)f2bf(pa0[2]); a[3] = (short)f2bf(pa0[3]);
        a[4] = (short)f2bf(pa1[0]); a[5] = (short)f2bf(pa1[1]);
        a[6] = (short)f2bf(pa1[2]); a[7] = (short)f2bf(pa1[3]);
        *(short8*)(&Ab[ar * LDP + aq * 8]) = a;
      } else {
#pragma unroll
        for (int cq = 0; cq < 4; ++cq) {
          ushortx4 v;
          v[0] = f2bf(pb0[cq]); v[1] = f2bf(pb1[cq]);
          v[2] = f2bf(pb2[cq]); v[3] = f2bf(pb3[cq]);
          *(ushortx4*)(&Bb[(c0 + cq) * LDP + kk0]) = v;
        }
      }
      __syncthreads();
      if (kk + 32 < 512) {
        if (t < 256) {
          const float* ap = X + (size_t)(rb + ar) * 512 + kk + 32 + aq * 8;
          pa0 = *(const floatx4*)(ap);
          pa1 = *(const floatx4*)(ap + 4);
        } else {
          const float* bp = Wk + (size_t)(kk + 32 + kk0) * 128 + c0;
          pb0 = *(const floatx4*)(bp);
          pb1 = *(const floatx4*)(bp + 128);
          pb2 = *(const floatx4*)(bp + 256);
          pb3 = *(const floatx4*)(bp + 384);
        }
      }
      short8 a0 = *(const short8*)(&Ab[(wr * 32      + lm) * LDP + lh * 8]);
      short8 a1 = *(const short8*)(&Ab[(wr * 32 + 16 + lm) * LDP + lh * 8]);
      short8 b0 = *(const short8*)(&Bb[(wc * 32      + lm) * LDP + lh * 8]);
      short8 b1 = *(const short8*)(&Bb[(wc * 32 + 16 + lm) * LDP + lh * 8]);
      acc[0][0] = __builtin_amdgcn_mfma_f32_16x16x32_bf16(a0, b0, acc[0][0], 0, 0, 0);
      acc[0][1] = __builtin_amdgcn_mfma_f32_16x16x32_bf16(a0, b1, acc[0][1], 0, 0, 0);
      acc[1][0] = __builtin_amdgcn_mfma_f32_16x16x32_bf16(a1, b0, acc[1][0], 0, 0, 0);
      acc[1][1] = __builtin_amdgcn_mfma_f32_16x16x32_bf16(a1, b1, acc[1][1], 0, 0, 0);
      __syncthreads();
    }
#pragma unroll
    for (int m = 0; m < 2; ++m)
#pragma unroll
      for (int n2 = 0; n2 < 2; ++n2)
#pragma unroll
        for (int j = 0; j < 4; ++j)
          Wh1bf[(size_t)(rb + wr * 32 + m * 16 + lh * 4 + j) * 512
                + hd * 128 + wc * 32 + n2 * 16 + lm] = f2bf(acc[m][n2][j]);
    float asv[2], adv[2];
#pragma unroll
    for (int n2 = 0; n2 < 2; ++n2) {
      asv[n2] = as1[hd * 128 + wc * 32 + n2 * 16 + lm];
      adv[n2] = ad1[hd * 128 + wc * 32 + n2 * 16 + lm];
    }
#pragma unroll
    for (int m = 0; m < 2; ++m)
#pragma unroll
      for (int j = 0; j < 4; ++j) {
        float ps = acc[m][0][j] * asv[0] + acc[m][1][j] * asv[1];
        float pd = acc[m][0][j] * adv[0] + acc[m][1][j] * adv[1];
#pragma unroll
        for (int off = 8; off >= 1; off >>= 1) {
          ps += __shfl_xor(ps, off, 16);
          pd += __shfl_xor(pd, off, 16);
        }
        if (lm == 0) {
          sps[wc][wr * 32 + m * 16 + lh * 4 + j] = ps;
          sds[wc][wr * 32 + m * 16 + lh * 4 + j] = pd;
        }
      }
    __syncthreads();
    if (t < 64) {
      src1t[(size_t)(rb + t) * 4 + hd] = sps[0][t] + sps[1][t] + sps[2][t] + sps[3][t];
      dst1t[(size_t)(rb + t) * 4 + hd] = sds[0][t] + sds[1][t] + sds[2][t] + sds[3][t];
    }
  }
}

// ---- D2: decode + 1-pass logits + pair-LDS + 16B gather + ELU + fused proj.
__global__ __launch_bounds__(256) void k_attn1(const u16b* __restrict__ mask,
    const u16b* __restrict__ Wh1bf,
    const float* __restrict__ src1t, const float* __restrict__ dst1t,
    const float* __restrict__ W2, const float* __restrict__ as2,
    const float* __restrict__ ad2, float* __restrict__ Wh2,
    float* __restrict__ src2, float* __restrict__ dst2) {
  int n = blockIdx.x, t = threadIdx.x, lane = t & 63, w = t >> 6;
  __shared__ u16b lst[512];
  __shared__ int2 pr[4][512];          // (byte-offset m*1024, normalized weight)
  __shared__ float h1row[512];
  __shared__ float redw[4][16];
  __shared__ int wtot[4];
  // ---- decode: thread t owns cols [16t,16t+16)
  unsigned M = mask[(size_t)n * 256 + t];
  int pc = __popc(M);
  int incl = pc;
#pragma unroll
  for (int off = 1; off <= 32; off <<= 1) {
    int v = __shfl_up(incl, off);
    if (lane >= off) incl += v;
  }
  if (lane == 63) wtot[w] = incl;
  float snw = src1t[n * 4 + w];
  __syncthreads();
  int base = 0;
  for (int w2 = 0; w2 < w; ++w2) base += wtot[w2];
  int cnt = wtot[0] + wtot[1] + wtot[2] + wtot[3];
  int pos = base + incl - pc;
  while (M) {
    int c = __builtin_ctz(M);
    lst[pos++] = (u16b)(t * 16 + c);
    M &= M - 1;
  }
  __syncthreads();
  // ---- single-pass logits in registers + per-wave online max/sum (head w)
  float ee[8];
  int mo[8];
  float mx = -1e30f, sm = 0.f;
#pragma unroll
  for (int rep = 0; rep < 8; ++rep) {
    int li = lane + rep * 64;
    if (li < cnt) {
      int m = lst[li];
      float e = snw + dst1t[m * 4 + w];
      e = e > 0.f ? e : 0.2f * e;
      ee[rep] = e; mo[rep] = m << 10;
      if (e > mx) { sm = sm * __expf(mx - e) + 1.f; mx = e; }
      else sm += __expf(e - mx);
    }
  }
#pragma unroll
  for (int off = 32; off >= 1; off >>= 1) {
    float mm = __shfl_xor(mx, off);
    float so = __shfl_xor(sm, off);
    float Mx = fmaxf(mx, mm);
    sm = sm * __expf(mx - Mx) + so * __expf(mm - Mx);
    mx = Mx;
  }
  float R = 1.f / sm;
#pragma unroll
  for (int rep = 0; rep < 8; ++rep) {
    int li = lane + rep * 64;
    if (li < cnt) {
      int2 pv;
      pv.x = mo[rep];
      pv.y = __float_as_int(__expf(ee[rep] - mx) * R);
      pr[w][li] = pv;
    }
  }
  __syncthreads();
  // ---- gather: wave w covers head-w cols; lane = q*16+p; q splits neighbors 4-way,
  //      p covers 8 cols via one 16B load. a[8] accumulators, shfl-reduced over q.
  int q = lane >> 4, p = lane & 15;
  const char* gbase = (const char*)Wh1bf + 256 * w + 16 * p;
  float a[8] = {0.f, 0.f, 0.f, 0.f, 0.f, 0.f, 0.f, 0.f};
  for (int li = q; li < cnt; li += 4) {
    int2 pw = pr[w][li];
    float wv = __int_as_float(pw.y);
    uintx4 u = *(const uintx4*)(gbase + pw.x);
    a[0] = fmaf(wv, bflo(u[0]), a[0]); a[1] = fmaf(wv, bfhi(u[0]), a[1]);
    a[2] = fmaf(wv, bflo(u[1]), a[2]); a[3] = fmaf(wv, bfhi(u[1]), a[3]);
    a[4] = fmaf(wv, bflo(u[2]), a[4]); a[5] = fmaf(wv, bfhi(u[2]), a[5]);
    a[6] = fmaf(wv, bflo(u[3]), a[6]); a[7] = fmaf(wv, bfhi(u[3]), a[7]);
  }
#pragma unroll
  for (int j = 0; j < 8; ++j) {
    a[j] += __shfl_xor(a[j], 16);
    a[j] += __shfl_xor(a[j], 32);
  }
  if (q == 0) {
#pragma unroll
    for (int j = 0; j < 8; ++j) {
      float v = a[j];
      v = v > 0.f ? v : __expf(v) - 1.f;         // ELU
      h1row[128 * w + 8 * p + j] = v;
    }
  }
  __syncthreads();
  // ---- fused layer-2 projection (per-wave partial over 128 inputs)
  {
    int o = lane & 15, ig = lane >> 4;
    float accw = 0.f;
    for (int i = w * 128 + ig; i < (w + 1) * 128; i += 4)
      accw = fmaf(h1row[i], W2[i * 16 + o], accw);
    accw += __shfl_xor(accw, 16);
    accw += __shfl_xor(accw, 32);
    if (lane < 16) redw[w][o] = accw;
  }
  __syncthreads();
  if (t < 16) {
    float v = redw[0][t] + redw[1][t] + redw[2][t] + redw[3][t];
    Wh2[n * 16 + t] = v;
    float ps = v * as2[t];
    float pd = v * ad2[t];
#pragma unroll
    for (int off = 8; off >= 1; off >>= 1) {
      ps += __shfl_xor(ps, off, 16);
      pd += __shfl_xor(pd, off, 16);
    }
    if (t == 0) { src2[n] = ps; dst2[n] = pd; }
  }
}

// ---- D3: fused decode+logits -> pair LDS -> attn + log_softmax. One wave/row.
__global__ __launch_bounds__(256) void k_attn2(const u16b* __restrict__ mask,
    const float* __restrict__ Wh2, const float* __restrict__ src2,
    const float* __restrict__ dst2, float* __restrict__ out) {
  int w = threadIdx.x >> 6, lane = threadIdx.x & 63;
  int n = blockIdx.x * 4 + w;
  __shared__ int2 pr4[4][512];         // (m*16, raw logit e)
  int2* pr = pr4[w];
  float snv = src2[n];
  unsigned long long B = *(const unsigned long long*)((const char*)mask + (size_t)n * 512 + lane * 8);
  int pc = __popcll(B);
  int incl = pc;
#pragma unroll
  for (int off = 1; off <= 32; off <<= 1) {
    int v = __shfl_up(incl, off);
    if (lane >= off) incl += v;
  }
  int cnt = __shfl(incl, 63);
  int pos = incl - pc;
  float mx = -1e30f, sm = 0.f;
  while (B) {
    int c = __builtin_ctzll(B);
    int m = lane * 64 + c;
    float e = snv + dst2[m];
    e = e > 0.f ? e : 0.2f * e;
    if (e > mx) { sm = sm * __expf(mx - e) + 1.f; mx = e; }
    else sm += __expf(e - mx);
    int2 pv; pv.x = m << 4; pv.y = __float_as_int(e);
    pr[pos++] = pv;
    B &= B - 1;
  }
#pragma unroll
  for (int off = 32; off >= 1; off >>= 1) {
    float mo = __shfl_xor(mx, off);
    float so = __shfl_xor(sm, off);
    float M = fmaxf(mx, mo);
    sm = sm * __expf(mx - M) + so * __expf(mo - M);
    mx = M;
  }
  float R = 1.f / sm;
  int o = lane & 15, g = lane >> 4;
  float acc = 0.f;
  for (int li = g; li < cnt; li += 4) {
    int2 pv = pr[li];
    float wgt = __expf(__int_as_float(pv.y) - mx) * R;
    acc = fmaf(wgt, Wh2[pv.x + o], acc);
  }
  acc += __shfl_xor(acc, 16);
  acc += __shfl_xor(acc, 32);
  float vm = acc;
#pragma unroll
  for (int off = 8; off >= 1; off >>= 1) vm = fmaxf(vm, __shfl_xor(vm, off, 16));
  float ex = __expf(acc - vm);
#pragma unroll
  for (int off = 8; off >= 1; off >>= 1) ex += __shfl_xor(ex, off, 16);
  if (lane < 16) out[(size_t)n * 16 + lane] = acc - vm - __logf(ex);
}

extern "C" void kernel_launch(void* const* d_in, const int* in_sizes, int n_in,
                              void* d_out, int out_size, void* d_ws, size_t ws_size,
                              hipStream_t stream) {
  const float* X   = (const float*)d_in[0];
  const float* adj = (const float*)d_in[1];
  const float* W1  = (const float*)d_in[2];
  const float* as1 = (const float*)d_in[3];
  const float* ad1 = (const float*)d_in[4];
  const float* W2  = (const float*)d_in[5];
  const float* as2 = (const float*)d_in[6];
  const float* ad2 = (const float*)d_in[7];
  float* out = (float*)d_out;

  // workspace (8 MB)
  char* ws = (char*)d_ws;
  float* src1t = (float*)ws;                         // 64 KB  [n][k]
  float* dst1t = (float*)(ws + (64 << 10));          // 64 KB  [n][k]
  float* src2  = (float*)(ws + (128 << 10));         // 16 KB
  float* dst2  = (float*)(ws + (144 << 10));         // 16 KB
  float* Wh2   = (float*)(ws + (160 << 10));         // 256 KB
  u16b*  mask  = (u16b*)(ws + (512 << 10));          // 2 MB   [n][256] u16 bitmask
  u16b*  Wh1bf = (u16b*)(ws + (4ull << 20));         // 4 MB   [n][k*128+h]

  k_fused1<<<dim3(2304), dim3(512), 0, stream>>>(adj, X, W1, as1, ad1,
                                                 mask, Wh1bf, src1t, dst1t);
  k_attn1<<<dim3(GN), dim3(256), 0, stream>>>(mask, Wh1bf, src1t, dst1t,
                                              W2, as2, ad2, Wh2, src2, dst2);
  k_attn2<<<dim3(1024), dim3(256), 0, stream>>>(mask, Wh2, src2, dst2, out);
}